// Round 7
// baseline (188.949 us; speedup 1.0000x reference)
//
#include <hip/hip_runtime.h>

#define B_   256
#define I_   1152
#define N_   10
#define P_   9216      // 8 * 1152
#define NO_  160       // 10 * 16

typedef unsigned short u16;
typedef short s8v __attribute__((ext_vector_type(8)));
typedef float f4v __attribute__((ext_vector_type(4)));

__device__ inline float bf2f(u16 u){
  unsigned v = ((unsigned)u) << 16; float f; __builtin_memcpy(&f, &v, 4); return f;
}
__device__ inline u16 f2bf(float f){
  unsigned b; __builtin_memcpy(&b, &f, 4);
  b += 0x7fffu + ((b >> 16) & 1u);   // RNE
  return (u16)(b >> 16);
}

// ---------------------------------------------------------------------------
// k_prep: grid 2464 x 256. (unchanged from R6 — proven)
//   blocks [0,160):  W[i][n][o][k] -> Wt[q=n*16+o][p=k*1152+i]=bf16(0.03W) and
//                    At0 = bf16(0.003W) (iter-0 c=0.1); blocks [0,45) zero bij.
//   blocks [160,2464): x fp32 [b][p] -> bf16 xbp[b][p] + xpb[p][b] (LDS transpose)
__global__ void k_prep(const float* __restrict__ x, const float* __restrict__ W,
                       u16* __restrict__ xbp, u16* __restrict__ xpb,
                       u16* __restrict__ Wt, u16* __restrict__ At,
                       float* __restrict__ bij){
  __shared__ float tile[32][36];
  int t = threadIdx.x, u = blockIdx.x;
  if (u < 160){
    if (u < 45) bij[u*256 + t] = 0.f;
    int q = u, n = q >> 4, o = q & 15;
    for (int i0 = 0; i0 < I_; i0 += 256){
      int i = i0 + t;
      if (i < I_){
        const float* src = W + (size_t)i*1280 + n*128 + o*8;
        float4 a = *reinterpret_cast<const float4*>(src);
        float4 b = *reinterpret_cast<const float4*>(src + 4);
        float vv[8] = {a.x,a.y,a.z,a.w,b.x,b.y,b.z,b.w};
        #pragma unroll
        for (int k = 0; k < 8; ++k){
          size_t addr = (size_t)q*P_ + (size_t)k*I_ + i;
          float wv = vv[k] * 0.03f;
          Wt[addr] = f2bf(wv);
          At[addr] = f2bf(wv * 0.1f);
        }
      }
    }
  } else {
    int b2 = u - 160;
    int tb = b2 & 7, tp = b2 >> 3;
    int b0 = tb << 5, p0 = tp << 5;
    int r = t >> 3, c4 = (t & 7) << 2;
    float4 v = *reinterpret_cast<const float4*>(x + (size_t)(b0 + r)*P_ + p0 + c4);
    *reinterpret_cast<float4*>(&tile[r][c4]) = v;
    uint2 pk;
    pk.x = (unsigned)f2bf(v.x) | ((unsigned)f2bf(v.y) << 16);
    pk.y = (unsigned)f2bf(v.z) | ((unsigned)f2bf(v.w) << 16);
    *reinterpret_cast<uint2*>(xbp + (size_t)(b0 + r)*P_ + p0 + c4) = pk;
    __syncthreads();
    float f0 = tile[c4+0][r], f1 = tile[c4+1][r], f2 = tile[c4+2][r], f3 = tile[c4+3][r];
    uint2 pk2;
    pk2.x = (unsigned)f2bf(f0) | ((unsigned)f2bf(f1) << 16);
    pk2.y = (unsigned)f2bf(f2) | ((unsigned)f2bf(f3) << 16);
    *reinterpret_cast<uint2*>(xpb + (size_t)(p0 + r)*B_ + b0 + c4) = pk2;
  }
}

// ---------------------------------------------------------------------------
// k_ssq: GEMM-S + split-K reduce + squash, all in-block.
// grid 160 (n = bid>>4, b-tile = bid&15), block 512 = 8 waves.
// Wave w: K-chunk p in [w*1152,(w+1)*1152), 36 MFMA (dual-acc, same loop body
// as R6 k_s). LDS reduce 8 partials -> squash over o -> out + bf16 v^T.
// NO in-loop scaling (At is pre-materialized) — discriminates the R5 mystery.
__global__ __launch_bounds__(512, 2) void k_ssq(
    const u16* __restrict__ xbp, const u16* __restrict__ At,
    float* __restrict__ out, u16* __restrict__ vbt){
  __shared__ float sred[8*64*4];        // 8 KB
  int t = threadIdx.x;
  int n = blockIdx.x >> 4, bx = blockIdx.x & 15;
  int b0 = bx << 4;
  int w = t >> 6, l = t & 63;
  int lo = l & 15, quad = l >> 4;
  const s8v* ap = reinterpret_cast<const s8v*>(xbp + (size_t)(b0 + lo)*P_ + w*1152 + quad*8);
  const s8v* bp = reinterpret_cast<const s8v*>(At  + (size_t)(n*16 + lo)*P_ + w*1152 + quad*8);
  f4v acc0 = {0.f,0.f,0.f,0.f}, acc1 = {0.f,0.f,0.f,0.f};
  #pragma unroll
  for (int s = 0; s < 18; ++s){
    s8v a0 = ap[8*s],     b0v = bp[8*s];
    s8v a1 = ap[8*s + 4], b1v = bp[8*s + 4];
    acc0 = __builtin_amdgcn_mfma_f32_16x16x32_bf16(a0, b0v, acc0, 0, 0, 0);
    acc1 = __builtin_amdgcn_mfma_f32_16x16x32_bf16(a1, b1v, acc1, 0, 0, 0);
  }
  f4v acc = acc0 + acc1;
  *reinterpret_cast<f4v*>(&sred[(w*64 + l)*4]) = acc;
  __syncthreads();
  if (t < 256){
    int o = t & 15, row = t >> 4;       // D row = quad*4+reg (C-layout)
    int qd = row >> 2, r = row & 3;
    float sv = 0.f;
    #pragma unroll
    for (int ww = 0; ww < 8; ++ww)
      sv += sred[(ww*64 + qd*16 + o)*4 + r];
    float sq = sv * sv;
    #pragma unroll
    for (int m = 8; m >= 1; m >>= 1) sq += __shfl_xor(sq, m, 16);
    float outv = sv * sqrtf(sq) / (1.0f + sq);
    int b = b0 + row;
    out[(size_t)b*NO_ + n*16 + o] = outv;   // final iteration's write survives
    vbt[(size_t)(n*16 + o)*B_ + b] = f2bf(outv);
  }
}

// ---------------------------------------------------------------------------
// k_ga: GEMM-G + bij update + softmax + At materialization, one dispatch.
// grid 72 (i-block of 16, owned EXCLUSIVELY -> no atomics), block 512 = 8
// waves (one per k). Wave k: G tile rows p = k*1152+i0+[0,16) over all 160 q
// (5 qp pairs), Wt-product + 16-lane o-reduce -> LDS red[k][n][il].
// Then: LDS k-reduce -> bij RMW (persists across dispatches) -> softmax for
// the 16 i's -> At[q][k][i-slice] = bf16(bf2f(Wt)*c) for all 160 q x 8 k.
__global__ __launch_bounds__(512, 2) void k_ga(
    const u16* __restrict__ xpb, const u16* __restrict__ vbt,
    const u16* __restrict__ Wt, float* __restrict__ bij,
    u16* __restrict__ At){
  __shared__ float red[8][10][16];      // 5 KB
  __shared__ float bnew[16][10];
  __shared__ float cmat[16][10];
  int t = threadIdx.x;
  int i0 = blockIdx.x << 4;
  int k = t >> 6, l = t & 63;
  int lo = l & 15, quad = l >> 4;
  int p0 = k*1152 + i0;
  const s8v* ap = reinterpret_cast<const s8v*>(xpb + (size_t)(p0 + lo)*B_ + quad*8);
  s8v a[8];
  #pragma unroll
  for (int s = 0; s < 8; ++s) a[s] = ap[4*s];
  #pragma unroll
  for (int qp = 0; qp < 5; ++qp){
    const s8v* bp0 = reinterpret_cast<const s8v*>(vbt + (size_t)((qp*2+0)*16 + lo)*B_ + quad*8);
    const s8v* bp1 = reinterpret_cast<const s8v*>(vbt + (size_t)((qp*2+1)*16 + lo)*B_ + quad*8);
    f4v acc0 = {0.f,0.f,0.f,0.f}, acc1 = {0.f,0.f,0.f,0.f};
    #pragma unroll
    for (int s = 0; s < 8; ++s){
      acc0 = __builtin_amdgcn_mfma_f32_16x16x32_bf16(a[s], bp0[4*s], acc0, 0, 0, 0);
      acc1 = __builtin_amdgcn_mfma_f32_16x16x32_bf16(a[s], bp1[4*s], acc1, 0, 0, 0);
    }
    #pragma unroll
    for (int s = 0; s < 2; ++s){
      f4v acc = s ? acc1 : acc0;
      int n = qp*2 + s;
      const u16* wp = Wt + (size_t)(n*16 + lo)*P_ + p0 + (quad << 2);
      ushort4 w4 = *reinterpret_cast<const ushort4*>(wp);
      float v0 = acc[0]*bf2f(w4.x), v1 = acc[1]*bf2f(w4.y);
      float v2 = acc[2]*bf2f(w4.z), v3 = acc[3]*bf2f(w4.w);
      #pragma unroll
      for (int m = 8; m >= 1; m >>= 1){
        v0 += __shfl_xor(v0, m, 16);
        v1 += __shfl_xor(v1, m, 16);
        v2 += __shfl_xor(v2, m, 16);
        v3 += __shfl_xor(v3, m, 16);
      }
      if (lo == 0){
        int il = quad << 2;             // D row = quad*4+reg = i_local
        red[k][n][il+0] = v0;
        red[k][n][il+1] = v1;
        red[k][n][il+2] = v2;
        red[k][n][il+3] = v3;
      }
    }
  }
  __syncthreads();
  if (t < 160){
    int il = t / 10, n = t - (t/10)*10;
    float dot = 0.f;
    #pragma unroll
    for (int kk = 0; kk < 8; ++kk) dot += red[kk][n][il];
    int i = i0 + il;
    float nb = bij[i*N_ + n] + dot * (1.f/256.f);
    bij[i*N_ + n] = nb;                 // exclusive ownership: plain RMW
    bnew[il][n] = nb;
  }
  __syncthreads();
  if (t < 16){
    float mx = bnew[t][0];
    #pragma unroll
    for (int nn = 1; nn < N_; ++nn) mx = fmaxf(mx, bnew[t][nn]);
    float e[N_], se = 0.f;
    #pragma unroll
    for (int nn = 0; nn < N_; ++nn){ e[nn] = __expf(bnew[t][nn] - mx); se += e[nn]; }
    float inv = 1.f / se;
    #pragma unroll
    for (int nn = 0; nn < N_; ++nn) cmat[t][nn] = e[nn] * inv;
  }
  __syncthreads();
  // At rewrite for this block's i-slice: 1280 (q,k) pairs x 16 i's.
  for (int pair = t; pair < 1280; pair += 512){
    int q = pair >> 3, kk = pair & 7;
    int n = q >> 4;
    size_t base = (size_t)q*P_ + (size_t)kk*I_ + i0;
    uint4 wa = *reinterpret_cast<const uint4*>(Wt + base);
    uint4 wb = *reinterpret_cast<const uint4*>(Wt + base + 8);
    uint4 ra, rb;
    ra.x = (unsigned)f2bf(bf2f(wa.x & 0xffff)*cmat[0][n])  | ((unsigned)f2bf(bf2f(wa.x >> 16)*cmat[1][n])  << 16);
    ra.y = (unsigned)f2bf(bf2f(wa.y & 0xffff)*cmat[2][n])  | ((unsigned)f2bf(bf2f(wa.y >> 16)*cmat[3][n])  << 16);
    ra.z = (unsigned)f2bf(bf2f(wa.z & 0xffff)*cmat[4][n])  | ((unsigned)f2bf(bf2f(wa.z >> 16)*cmat[5][n])  << 16);
    ra.w = (unsigned)f2bf(bf2f(wa.w & 0xffff)*cmat[6][n])  | ((unsigned)f2bf(bf2f(wa.w >> 16)*cmat[7][n])  << 16);
    rb.x = (unsigned)f2bf(bf2f(wb.x & 0xffff)*cmat[8][n])  | ((unsigned)f2bf(bf2f(wb.x >> 16)*cmat[9][n])  << 16);
    rb.y = (unsigned)f2bf(bf2f(wb.y & 0xffff)*cmat[10][n]) | ((unsigned)f2bf(bf2f(wb.y >> 16)*cmat[11][n]) << 16);
    rb.z = (unsigned)f2bf(bf2f(wb.z & 0xffff)*cmat[12][n]) | ((unsigned)f2bf(bf2f(wb.z >> 16)*cmat[13][n]) << 16);
    rb.w = (unsigned)f2bf(bf2f(wb.w & 0xffff)*cmat[14][n]) | ((unsigned)f2bf(bf2f(wb.w >> 16)*cmat[15][n]) << 16);
    *reinterpret_cast<uint4*>(At + base)     = ra;
    *reinterpret_cast<uint4*>(At + base + 8) = rb;
  }
}

// ---------------------------------------------------------------------------
extern "C" void kernel_launch(void* const* d_in, const int* in_sizes, int n_in,
                              void* d_out, int out_size, void* d_ws, size_t ws_size,
                              hipStream_t stream){
  (void)in_sizes; (void)n_in; (void)out_size; (void)ws_size;
  const float* x = (const float*)d_in[0];   // (256, 8, 1152)
  const float* W = (const float*)d_in[1];   // (1, 1152, 10, 16, 8)
  float* out = (float*)d_out;               // (256, 10, 16, 1) fp32

  float* bij = (float*)d_ws;                // 11520 fp32
  u16* xbp = (u16*)(bij + 11520);           // 2359296 bf16
  u16* xpb = xbp + 2359296;                 // 2359296
  u16* Wt  = xpb + 2359296;                 // 1474560
  u16* At  = Wt  + 1474560;                 // 1474560
  u16* vbt = At  + 1474560;                 // 40960

  k_prep<<<2464, 256, 0, stream>>>(x, W, xbp, xpb, Wt, At, bij);
  for (int it = 0; it < 3; ++it){
    k_ssq<<<160, 512, 0, stream>>>(xbp, At, out, vbt);
    if (it < 2)
      k_ga<<<72, 512, 0, stream>>>(xpb, vbt, Wt, bij, At);
  }
}

// Round 9
// 143.176 us; speedup vs baseline: 1.3197x; 1.3197x over previous
//
#include <hip/hip_runtime.h>

#define B_   256
#define I_   1152
#define N_   10
#define P_   9216      // 8 * 1152
#define NO_  160       // 10 * 16

typedef unsigned short u16;
typedef short s8v __attribute__((ext_vector_type(8)));
typedef float f4v __attribute__((ext_vector_type(4)));

__device__ inline float bf2f(u16 u){
  unsigned v = ((unsigned)u) << 16; float f; __builtin_memcpy(&f, &v, 4); return f;
}
__device__ inline u16 f2bf(float f){
  unsigned b; __builtin_memcpy(&b, &f, 4);
  b += 0x7fffu + ((b >> 16) & 1u);   // RNE
  return (u16)(b >> 16);
}

// ---------------------------------------------------------------------------
// k_prep: grid 2464 x 256. (unchanged — proven through R6/R7)
//   blocks [0,160):  W[i][n][o][k] -> Wt[q=n*16+o][p=k*1152+i]=bf16(0.03W);
//                    blocks [0,45) also zero bij (softmax(0) -> c=0.1, so
//                    iteration 0 needs no special case downstream).
//   blocks [160,2464): x fp32 [b][p] -> bf16 xbp[b][p] + xpb[p][b] (LDS transpose)
__global__ void k_prep(const float* __restrict__ x, const float* __restrict__ W,
                       u16* __restrict__ xbp, u16* __restrict__ xpb,
                       u16* __restrict__ Wt, float* __restrict__ bij){
  __shared__ float tile[32][36];
  int t = threadIdx.x, u = blockIdx.x;
  if (u < 160){
    if (u < 45) bij[u*256 + t] = 0.f;
    int q = u, n = q >> 4, o = q & 15;
    for (int i0 = 0; i0 < I_; i0 += 256){
      int i = i0 + t;
      if (i < I_){
        const float* src = W + (size_t)i*1280 + n*128 + o*8;
        float4 a = *reinterpret_cast<const float4*>(src);
        float4 b = *reinterpret_cast<const float4*>(src + 4);
        float vv[8] = {a.x,a.y,a.z,a.w,b.x,b.y,b.z,b.w};
        #pragma unroll
        for (int k = 0; k < 8; ++k)
          Wt[(size_t)q*P_ + (size_t)k*I_ + i] = f2bf(vv[k] * 0.03f);
      }
    }
  } else {
    int b2 = u - 160;
    int tb = b2 & 7, tp = b2 >> 3;
    int b0 = tb << 5, p0 = tp << 5;
    int r = t >> 3, c4 = (t & 7) << 2;
    float4 v = *reinterpret_cast<const float4*>(x + (size_t)(b0 + r)*P_ + p0 + c4);
    *reinterpret_cast<float4*>(&tile[r][c4]) = v;
    uint2 pk;
    pk.x = (unsigned)f2bf(v.x) | ((unsigned)f2bf(v.y) << 16);
    pk.y = (unsigned)f2bf(v.z) | ((unsigned)f2bf(v.w) << 16);
    *reinterpret_cast<uint2*>(xbp + (size_t)(b0 + r)*P_ + p0 + c4) = pk;
    __syncthreads();
    float f0 = tile[c4+0][r], f1 = tile[c4+1][r], f2 = tile[c4+2][r], f3 = tile[c4+3][r];
    uint2 pk2;
    pk2.x = (unsigned)f2bf(f0) | ((unsigned)f2bf(f1) << 16);
    pk2.y = (unsigned)f2bf(f2) | ((unsigned)f2bf(f3) << 16);
    *reinterpret_cast<uint2*>(xpb + (size_t)(p0 + r)*B_ + b0 + c4) = pk2;
  }
}

// ---------------------------------------------------------------------------
// k_s2: GEMM-S with in-LDS softmax + B-scaling pre-phase (replaces k_at+k_s).
// grid (8,10,16) x 128 = 1280 blocks, 2 waves each.
// Block: b-pair bx2 (wave w owns b-tile b0 = bx2*32+w*16), n, K-chunk kc
// (576 p). i-range of chunk = (kc&1)*576 + [0,576)  (chunk never spans k).
// Phase 1: c_lds[j] = softmax_n(bij[i0+j][:]).
// Phase 2: Bt[r][col] = bf16(bf2f(Wt[n*16+r][kc*576+col]) * c_lds[col]),
//          ALL 16x576 = 1152 uint4 units (R8 bug #1: only 576 were staged).
// Phase 3: 9 dual-acc MFMA steps = 576 K (R8 bug #2: had 18 steps = OOB).
//          Row pad 584 keeps ds_read_b128 16B-aligned (1168 = 73*16).
__global__ __launch_bounds__(128) void k_s2(
    const u16* __restrict__ xbp, const u16* __restrict__ Wt,
    const float* __restrict__ bij, float* __restrict__ s_part){
  __shared__ u16  Bt[16][584];          // 18.25 KB
  __shared__ float c_lds[576];          // 2.25 KB
  int t = threadIdx.x;
  int bx2 = blockIdx.x, n = blockIdx.y, kc = blockIdx.z;
  int i0 = (kc & 1) * 576;

  // phase 1: softmax component n for this chunk's 576 i's
  for (int j = t; j < 576; j += 128){
    const float* br = bij + (size_t)(i0 + j)*N_;
    float l0 = br[0], l1 = br[1], l2 = br[2], l3 = br[3], l4 = br[4];
    float l5 = br[5], l6 = br[6], l7 = br[7], l8 = br[8], l9 = br[9];
    float mx = fmaxf(fmaxf(fmaxf(fmaxf(l0,l1),fmaxf(l2,l3)),
                           fmaxf(fmaxf(l4,l5),fmaxf(l6,l7))), fmaxf(l8,l9));
    float e0=__expf(l0-mx), e1=__expf(l1-mx), e2=__expf(l2-mx), e3=__expf(l3-mx), e4=__expf(l4-mx);
    float e5=__expf(l5-mx), e6=__expf(l6-mx), e7=__expf(l7-mx), e8=__expf(l8-mx), e9=__expf(l9-mx);
    float se = e0+e1+e2+e3+e4+e5+e6+e7+e8+e9;
    float ev[10] = {e0,e1,e2,e3,e4,e5,e6,e7,e8,e9};
    c_lds[j] = ev[n] / se;
  }
  __syncthreads();

  // phase 2: stage scaled B-tile — 1152 uint4 units (16 rows x 72 units), 9/thread
  for (int u = t; u < 1152; u += 128){
    int r = u / 72, cb = (u - r*72) * 8;
    uint4 w = *reinterpret_cast<const uint4*>(Wt + (size_t)(n*16 + r)*P_ + kc*576 + cb);
    float4 c0 = *reinterpret_cast<const float4*>(&c_lds[cb]);
    float4 c1 = *reinterpret_cast<const float4*>(&c_lds[cb + 4]);
    uint4 rr;
    rr.x = (unsigned)f2bf(bf2f(w.x & 0xffff)*c0.x) | ((unsigned)f2bf(bf2f(w.x >> 16)*c0.y) << 16);
    rr.y = (unsigned)f2bf(bf2f(w.y & 0xffff)*c0.z) | ((unsigned)f2bf(bf2f(w.y >> 16)*c0.w) << 16);
    rr.z = (unsigned)f2bf(bf2f(w.z & 0xffff)*c1.x) | ((unsigned)f2bf(bf2f(w.z >> 16)*c1.y) << 16);
    rr.w = (unsigned)f2bf(bf2f(w.w & 0xffff)*c1.z) | ((unsigned)f2bf(bf2f(w.w >> 16)*c1.w) << 16);
    *reinterpret_cast<uint4*>(&Bt[r][cb]) = rr;
  }
  __syncthreads();

  // phase 3: MFMA loop, 9 dual-acc steps = 576 K (B from LDS)
  int w = t >> 6, l = t & 63;
  int lo = l & 15, quad = l >> 4;
  int b0 = bx2*32 + w*16;
  const s8v* ap = reinterpret_cast<const s8v*>(xbp + (size_t)(b0 + lo)*P_ + kc*576 + quad*8);
  f4v acc0 = {0.f,0.f,0.f,0.f}, acc1 = {0.f,0.f,0.f,0.f};
  #pragma unroll
  for (int s = 0; s < 9; ++s){
    s8v a0 = ap[8*s];
    s8v b0v = *reinterpret_cast<const s8v*>(&Bt[lo][quad*8 + 64*s]);
    s8v a1 = ap[8*s + 4];
    s8v b1v = *reinterpret_cast<const s8v*>(&Bt[lo][quad*8 + 64*s + 32]);
    acc0 = __builtin_amdgcn_mfma_f32_16x16x32_bf16(a0, b0v, acc0, 0, 0, 0);
    acc1 = __builtin_amdgcn_mfma_f32_16x16x32_bf16(a1, b1v, acc1, 0, 0, 0);
  }
  f4v acc = acc0 + acc1;
  float* op = s_part + (size_t)kc*40960;
  int r0 = quad << 2;
  #pragma unroll
  for (int r = 0; r < 4; ++r)
    op[(size_t)(b0 + r0 + r)*NO_ + n*16 + lo] = acc[r];
}

// ---------------------------------------------------------------------------
// k_sq: reduce 16 split-K partials, squash over O per (b,n) row, write fp32
// out and bf16 v^T[q][b]. grid 160 x 256. (unchanged)
__global__ void k_sq(const float* __restrict__ s_part, float* __restrict__ out,
                     u16* __restrict__ vbt){
  int t = threadIdx.x;
  int o = t & 15, rl = t >> 4;
  int rowid = blockIdx.x*16 + rl;          // b*10+n
  int b = rowid / 10, n = rowid - b*10;
  size_t idx = (size_t)b*NO_ + n*16 + o;
  float sv = 0.f;
  #pragma unroll
  for (int c = 0; c < 16; ++c) sv += s_part[idx + (size_t)c*40960];
  float sq = sv * sv;
  #pragma unroll
  for (int m = 8; m >= 1; m >>= 1) sq += __shfl_xor(sq, m, 16);
  float outv = sv * sqrtf(sq) / (1.0f + sq);
  out[idx] = outv;                         // final iteration's write survives
  vbt[(size_t)(n*16 + o)*B_ + b] = f2bf(outv);
}

// ---------------------------------------------------------------------------
// k_g: G[p][q] = sum_b xpb[p][b]*vbt[q][b] (never materialized); multiply by
// Wt fragment in-register, shuffle-sum over o-lanes, atomicAdd into bij[i][n]
// (accumulates across iterations). grid 720 x 256. (unchanged)
__global__ void k_g(const u16* __restrict__ xpb, const u16* __restrict__ vbt,
                    const u16* __restrict__ Wt, float* __restrict__ bij){
  int w = blockIdx.x*4 + (threadIdx.x >> 6);
  int l = threadIdx.x & 63;
  int pt = w % 576, qp = w / 576;
  int p0 = pt << 4;
  int lo = l & 15, quad = l >> 4;
  const s8v* ap  = reinterpret_cast<const s8v*>(xpb + (size_t)(p0 + lo)*B_ + quad*8);
  const s8v* bp0 = reinterpret_cast<const s8v*>(vbt + (size_t)((qp*2+0)*16 + lo)*B_ + quad*8);
  const s8v* bp1 = reinterpret_cast<const s8v*>(vbt + (size_t)((qp*2+1)*16 + lo)*B_ + quad*8);
  f4v acc0 = {0.f,0.f,0.f,0.f}, acc1 = {0.f,0.f,0.f,0.f};
  #pragma unroll
  for (int s = 0; s < 8; ++s){
    s8v a  = ap[4*s];
    s8v b0 = bp0[4*s];
    s8v b1 = bp1[4*s];
    acc0 = __builtin_amdgcn_mfma_f32_16x16x32_bf16(a, b0, acc0, 0, 0, 0);
    acc1 = __builtin_amdgcn_mfma_f32_16x16x32_bf16(a, b1, acc1, 0, 0, 0);
  }
  int ib = p0 % 1152;                      // p-tile never spans k (1152%16==0)
  #pragma unroll
  for (int s = 0; s < 2; ++s){
    f4v acc = s ? acc1 : acc0;
    int n = qp*2 + s;
    const u16* wp = Wt + (size_t)(n*16 + lo)*P_ + p0 + (quad << 2);
    ushort4 w4 = *reinterpret_cast<const ushort4*>(wp);
    float v0 = acc[0]*bf2f(w4.x), v1 = acc[1]*bf2f(w4.y);
    float v2 = acc[2]*bf2f(w4.z), v3 = acc[3]*bf2f(w4.w);
    #pragma unroll
    for (int m = 8; m >= 1; m >>= 1){
      v0 += __shfl_xor(v0, m, 16);
      v1 += __shfl_xor(v1, m, 16);
      v2 += __shfl_xor(v2, m, 16);
      v3 += __shfl_xor(v3, m, 16);
    }
    if (lo == 0){
      int i = ib + (quad << 2);
      atomicAdd(&bij[(i+0)*N_ + n], v0 * (1.f/256.f));
      atomicAdd(&bij[(i+1)*N_ + n], v1 * (1.f/256.f));
      atomicAdd(&bij[(i+2)*N_ + n], v2 * (1.f/256.f));
      atomicAdd(&bij[(i+3)*N_ + n], v3 * (1.f/256.f));
    }
  }
}

// ---------------------------------------------------------------------------
extern "C" void kernel_launch(void* const* d_in, const int* in_sizes, int n_in,
                              void* d_out, int out_size, void* d_ws, size_t ws_size,
                              hipStream_t stream){
  (void)in_sizes; (void)n_in; (void)out_size; (void)ws_size;
  const float* x = (const float*)d_in[0];   // (256, 8, 1152)
  const float* W = (const float*)d_in[1];   // (1, 1152, 10, 16, 8)
  float* out = (float*)d_out;               // (256, 10, 16, 1) fp32

  float* s_part = (float*)d_ws;             // 16 * 40960 fp32
  float* bij    = s_part + 16*40960;        // 11520 fp32
  u16* xbp = (u16*)(bij + 11520);           // 2359296 bf16
  u16* xpb = xbp + 2359296;                 // 2359296
  u16* Wt  = xpb + 2359296;                 // 1474560
  u16* vbt = Wt  + 1474560;                 // 40960

  k_prep<<<2464, 256, 0, stream>>>(x, W, xbp, xpb, Wt, bij);
  for (int it = 0; it < 3; ++it){
    k_s2<<<dim3(8, 10, 16), 128, 0, stream>>>(xbp, Wt, bij, s_part);
    k_sq<<<160, 256, 0, stream>>>(s_part, out, vbt);
    if (it < 2)
      k_g<<<720, 256, 0, stream>>>(xpb, vbt, Wt, bij);
  }
}